// Round 14
// baseline (2350.578 us; speedup 1.0000x reference)
//
#include <hip/hip_runtime.h>
#include <hip/hip_bf16.h>
#include <math.h>

#define IGNORE_INDEX (-100)

constexpr int BT = 2048, H = 4096, V = 32000;
constexpr int BM = 128, BN = 128, BK = 64;
constexpr int KT = H / BK;            // 64 k-tiles
constexpr int MT = BT / BM;           // 16
constexpr int NT = V / BN;            // 250
constexpr int NCHUNK = NT * 2;        // 500 partial chunks/row (64 cols each)

typedef int   i32x4  __attribute__((ext_vector_type(4)));
typedef int   i32x8  __attribute__((ext_vector_type(8)));
typedef float f32x16 __attribute__((ext_vector_type(16)));

// e8m0 scale byte for 2^-7 (operands are pre-scaled by 2^7 at conversion)
#define SC8 120

__device__ __forceinline__ void gload_lds16(const char* g, char* l) {
  __builtin_amdgcn_global_load_lds(
      (const __attribute__((address_space(1))) unsigned int*)(g),
      (__attribute__((address_space(3))) unsigned int*)(l), 16, 0, 0);
}

#define BAR()        asm volatile("s_barrier" ::: "memory")
#define WAIT_VM(N)   asm volatile("s_waitcnt vmcnt(" #N ")" ::: "memory")
#define SB0()        __builtin_amdgcn_sched_barrier(0)

// ---------------------------------------------------------------------------
// fp32 -> fp8 e4m3 bulk convert with x128 pre-scale (W: linear (V,H) layout)
// ---------------------------------------------------------------------------
__global__ __launch_bounds__(256)
void convert_fp8(const float* __restrict__ src, char* __restrict__ dst,
                 int n8) {
  int i = blockIdx.x * blockDim.x + threadIdx.x;
  const int stride = gridDim.x * blockDim.x;
  for (; i < n8; i += stride) {
    const float4 f0 = ((const float4*)src)[2 * i];
    const float4 f1 = ((const float4*)src)[2 * i + 1];
    const float S = 128.f;
    int lo = 0, hi = 0;
    lo = __builtin_amdgcn_cvt_pk_fp8_f32(f0.x * S, f0.y * S, lo, false);
    lo = __builtin_amdgcn_cvt_pk_fp8_f32(f0.z * S, f0.w * S, lo, true);
    hi = __builtin_amdgcn_cvt_pk_fp8_f32(f1.x * S, f1.y * S, hi, false);
    hi = __builtin_amdgcn_cvt_pk_fp8_f32(f1.z * S, f1.w * S, hi, true);
    int2 v; v.x = lo; v.y = hi;
    ((int2*)dst)[i] = v;
  }
}

// ---------------------------------------------------------------------------
// X: fp32 -> fp8 into MFMA-fragment-tiled layout (r12-verified):
// Xt[rg = row>>5][kt = k>>6][lane = (row&31) + 32*((k>>5)&1)][k&31]
// ---------------------------------------------------------------------------
__global__ __launch_bounds__(256)
void convert_x_fp8_tiled(const float* __restrict__ src,
                         char* __restrict__ dst, int n8) {
  int i = blockIdx.x * blockDim.x + threadIdx.x;
  const int stride = gridDim.x * blockDim.x;
  for (; i < n8; i += stride) {
    const float4 f0 = ((const float4*)src)[2 * i];
    const float4 f1 = ((const float4*)src)[2 * i + 1];
    const float S = 128.f;
    int lo = 0, hi = 0;
    lo = __builtin_amdgcn_cvt_pk_fp8_f32(f0.x * S, f0.y * S, lo, false);
    lo = __builtin_amdgcn_cvt_pk_fp8_f32(f0.z * S, f0.w * S, lo, true);
    hi = __builtin_amdgcn_cvt_pk_fp8_f32(f1.x * S, f1.y * S, hi, false);
    hi = __builtin_amdgcn_cvt_pk_fp8_f32(f1.z * S, f1.w * S, hi, true);
    int2 v; v.x = lo; v.y = hi;
    const int r  = i >> 9;            // row (H/8 = 512 octets per row)
    const int k0 = (i & 511) * 8;     // k-byte offset in row
    const int lane = (r & 31) + ((k0 >> 5) & 1) * 32;
    const size_t addr =
        ((size_t)((r >> 5) * 64 + (k0 >> 6)) * 64 + lane) * 32 + (k0 & 31);
    *(int2*)(dst + addr) = v;
  }
}

// ---------------------------------------------------------------------------
// 128x128 MX-fp8 GEMM, 4-wave blocks, SPILL-FREE de-lockstep (r14):
// launch_bounds(256,2) caps VGPR at 256 (floor-only); register demand
// ~111 (acc 64 + A 16 + B 16 + addr) -> compiler lands <=128 -> HW runs
// 4 waves/SIMD = 4 independent blocks/CU (LDS 4x16KB).
// A: single reg set loaded per-phase direct from L1/L2 (latency hidden by
// cross-block TLP). B: LDS double-buffer, r11-verified swizzle.
// Phase(t): LOADA(t); VM(4) [drains prior B stages: order prior-B(2) < A(4)];
//           STAGE_B(buf^1,t+1); RDB(buf); MFMA; SB0; BAR.
// MFMA's compiler vmcnt(2) for A leaves this phase's B-stages in flight
// across BAR (T4). Overwrite audit: stage(buf^1)@t after BAR(t-1); buf^1's
// last reads pinned before BAR(t-1) by SB0+operand waits. (r12/r13 pattern)
// ---------------------------------------------------------------------------
__global__ __launch_bounds__(256, 2)
void gemm_lse_128(const char* __restrict__ Wq,   // (V,H) fp8 linear
                  const char* __restrict__ Xt,   // tiled fp8 (8 MB)
                  const int* __restrict__ target,
                  const float* __restrict__ bias,
                  float* __restrict__ pM, float* __restrict__ pS,
                  float* __restrict__ gold)
{
  __shared__ char Bs[16384];   // [buf:2][128 rows][64 B]

  const int tid  = threadIdx.x;
  const int lane = tid & 63;
  const int wid  = tid >> 6;        // 0..3
  const int wr   = wid >> 1;        // 0..1 : rows [wr*64, +64)
  const int wc   = wid & 1;         // 0..1 : cols [wc*64, +64)

  // XCD swizzle: nwg = 4000 = 8*500, bijective
  const int bid = (int)blockIdx.x;
  const int swz = (bid & 7) * 500 + (bid >> 3);
  const int mt = swz & (MT - 1);
  const int nt = swz >> 4;
  const int m0 = mt * BM, n0 = nt * BN;

  const int l31 = lane & 31;
  const int h   = lane >> 5;
  // B read swizzle (r11-verified): slot(row,q) = q ^ ((row>>1)&3)
  const int r2  = (l31 >> 1) & 3;
  const int s0  = ((2 * h) ^ r2) << 4;
  const int s1  = ((2 * h + 1) ^ r2) << 4;
  const int bbase = (wc * 64 + l31) * 64;

  // B staging: lane covers row lane>>2, slot lane&3; source pre-swizzled
  const int srow  = lane >> 2;
  const int sslot = ((lane & 3) ^ ((lane >> 3) & 3)) << 4;
  const char* bsrc = Wq + (size_t)(n0 + wid * 32 + srow) * H + sslot;

  // A direct: row-group base for this wave; per-lane byte offset
  const int rg0 = mt * 4 + wr * 2;
  const int aoff = lane * 32;

  f32x16 acc[4] = {};               // [mi*2 + nj]
  i32x8 aC[2], bF0, bF1;

#define STAGE_B(BUF, T)                                                       \
  { gload_lds16(bsrc + (T) * BK,                                              \
                &Bs[(BUF) * 8192 + wid * 2048 + lane * 16]);                  \
    gload_lds16(bsrc + (size_t)16 * H + (T) * BK,                             \
                &Bs[(BUF) * 8192 + wid * 2048 + 1024 + lane * 16]); }

#define RDB(DST, BUF, NJ)                                                     \
  { i32x4 lo = *(const i32x4*)&Bs[(BUF) * 8192 + bbase + (NJ) * 2048 + s0];   \
    i32x4 hi = *(const i32x4*)&Bs[(BUF) * 8192 + bbase + (NJ) * 2048 + s1];   \
    DST[0] = lo[0]; DST[1] = lo[1]; DST[2] = lo[2]; DST[3] = lo[3];           \
    DST[4] = hi[0]; DST[5] = hi[1]; DST[6] = hi[2]; DST[7] = hi[3]; }

#define LOADA(DST, T)                                                         \
  { _Pragma("unroll")                                                         \
    for (int mi = 0; mi < 2; ++mi) {                                          \
      const char* ap = Xt + ((size_t)((rg0 + mi) * 64 + (T)) << 11) + aoff;   \
      i32x4 lo = *(const i32x4*)(ap);                                         \
      i32x4 hi = *(const i32x4*)(ap + 16);                                    \
      DST[mi][0]=lo[0]; DST[mi][1]=lo[1]; DST[mi][2]=lo[2]; DST[mi][3]=lo[3]; \
      DST[mi][4]=hi[0]; DST[mi][5]=hi[1]; DST[mi][6]=hi[2]; DST[mi][7]=hi[3]; \
    } }

#define MFMA4(ASET)                                                           \
  { __builtin_amdgcn_s_setprio(1);                                            \
    _Pragma("unroll")                                                         \
    for (int mi = 0; mi < 2; ++mi) {                                          \
      acc[mi*2+0] = __builtin_amdgcn_mfma_scale_f32_32x32x64_f8f6f4(          \
          ASET[mi], bF0, acc[mi*2+0], 0, 0, 0, SC8, 0, SC8);                  \
      acc[mi*2+1] = __builtin_amdgcn_mfma_scale_f32_32x32x64_f8f6f4(          \
          ASET[mi], bF1, acc[mi*2+1], 0, 0, 0, SC8, 0, SC8);                  \
    }                                                                         \
    __builtin_amdgcn_s_setprio(0); }

  // ---- prologue: B(0) -> buf0, drain, barrier
  STAGE_B(0, 0);
  WAIT_VM(0);
  BAR();

  // ---- main loop: 2 K-tiles/iter (even: buf0, odd: buf1), 1 barrier each
  for (int t = 0; t < KT - 2; t += 2) {
    // tile t (buf0)
    LOADA(aC, t);
    WAIT_VM(4);                    // drains prior-phase B stages (2)
    STAGE_B(1, t + 1);
    RDB(bF0, 0, 0); RDB(bF1, 0, 1);
    MFMA4(aC);
    SB0(); BAR();
    // tile t+1 (buf1)
    LOADA(aC, t + 1);
    WAIT_VM(4);
    STAGE_B(0, t + 2);
    RDB(bF0, 1, 0); RDB(bF1, 1, 1);
    MFMA4(aC);
    SB0(); BAR();
  }
  // ---- tail: tile KT-2 (buf0, stage KT-1), tile KT-1 (buf1)
  LOADA(aC, KT - 2);
  WAIT_VM(4);
  STAGE_B(1, KT - 1);
  RDB(bF0, 0, 0); RDB(bF1, 0, 1);
  MFMA4(aC);
  SB0(); BAR();
  LOADA(aC, KT - 1);
  WAIT_VM(4);                      // drains the last 2 B stages
  RDB(bF0, 1, 0); RDB(bF1, 1, 1);
  MFMA4(aC);

#undef STAGE_B
#undef RDB
#undef LOADA
#undef MFMA4

  // ---- epilogue (32x32 C/D: col=lane&31, row=(r&3)+8*(r>>2)+4*h) — verified
  const int colbase = n0 + wc * 64;
  float bv[2];
#pragma unroll
  for (int nj = 0; nj < 2; ++nj) bv[nj] = bias[colbase + nj * 32 + l31];

  const int chunk = nt * 2 + wc;
#pragma unroll
  for (int mi = 0; mi < 2; ++mi) {
#pragma unroll
    for (int r = 0; r < 16; ++r) {
      const int row = m0 + wr * 64 + mi * 32 + (r & 3) + 8 * (r >> 2) + 4 * h;
      const float v0 = acc[mi * 2 + 0][r] + bv[0];
      const float v1 = acc[mi * 2 + 1][r] + bv[1];
      float mx = fmaxf(v0, v1);
#pragma unroll
      for (int d = 1; d < 32; d <<= 1) mx = fmaxf(mx, __shfl_xor(mx, d));
      float s = expf(v0 - mx) + expf(v1 - mx);
#pragma unroll
      for (int d = 1; d < 32; d <<= 1) s += __shfl_xor(s, d);
      if (l31 == 0) {
        pM[(size_t)row * NCHUNK + chunk] = mx;
        pS[(size_t)row * NCHUNK + chunk] = s;
      }
      const int t = target[row];
      const int d0 = t - colbase;
      if (d0 >= 0 && d0 < 64 && l31 == (d0 & 31)) {
        gold[row] = (d0 >> 5) ? v1 : v0;
      }
    }
  }
}

// one wave per row: combine 500 (max, sumexp) chunks -> rowterm
__global__ __launch_bounds__(256)
void reduce_lse(const float* __restrict__ pM, const float* __restrict__ pS,
                const float* __restrict__ gold, const int* __restrict__ target,
                const float* __restrict__ lw, float* __restrict__ rowterm)
{
  const int wid = threadIdx.x >> 6, lane = threadIdx.x & 63;
  const int row = blockIdx.x * 4 + wid;
  if (row >= BT) return;
  const float* pm = pM + (size_t)row * NCHUNK;
  const float* ps = pS + (size_t)row * NCHUNK;
  float m = -INFINITY;
  for (int c2 = lane; c2 < NCHUNK; c2 += 64) m = fmaxf(m, pm[c2]);
#pragma unroll
  for (int d = 1; d < 64; d <<= 1) m = fmaxf(m, __shfl_xor(m, d));
  float s = 0.f;
  for (int c2 = lane; c2 < NCHUNK; c2 += 64) s += ps[c2] * expf(pm[c2] - m);
#pragma unroll
  for (int d = 1; d < 64; d <<= 1) s += __shfl_xor(s, d);
  if (lane == 0) {
    const int t = target[row];
    float term = 0.f;
    if (t != IGNORE_INDEX) term = (m + logf(s) - gold[row]) * lw[row];
    rowterm[row] = term;
  }
}

// single-block deterministic finalize
__global__ __launch_bounds__(256)
void finalize(const float* __restrict__ rowterm, const int* __restrict__ target,
              const float* __restrict__ rsw, const int* __restrict__ gas,
              float* __restrict__ out)
{
  __shared__ float sred[4];
  __shared__ int cred[4];
  const int tid = threadIdx.x;
  float s = 0.f;
  int cnt = 0;
  for (int i = tid; i < BT; i += 256) {
    s += rowterm[i];
    cnt += (target[i] != IGNORE_INDEX) ? 1 : 0;
  }
#pragma unroll
  for (int d = 1; d < 64; d <<= 1) {
    s += __shfl_xor(s, d);
    cnt += __shfl_xor(cnt, d);
  }
  const int wid = tid >> 6, lane = tid & 63;
  if (lane == 0) { sred[wid] = s; cred[wid] = cnt; }
  __syncthreads();
  if (tid == 0) {
    const float st = sred[0] + sred[1] + sred[2] + sred[3];
    const int ct = cred[0] + cred[1] + cred[2] + cred[3];
    const float n = (float)((ct > 0) ? ct : 1);
    const float rs = rsw[0];
    float loss = (rs == 0.f) ? 0.f : (st / n) / rs;
    loss /= (float)gas[0];
    out[0] = loss;
  }
}

extern "C" void kernel_launch(void* const* d_in, const int* in_sizes, int n_in,
                              void* d_out, int out_size, void* d_ws, size_t ws_size,
                              hipStream_t stream)
{
  const float* Wt     = (const float*)d_in[0];  // lin_weight (V,H)
  const float* X      = (const float*)d_in[1];  // _input (BT,H)
  const int*   target = (const int*)d_in[2];
  const float* bias   = (const float*)d_in[3];
  const float* lw     = (const float*)d_in[4];
  const float* rsw    = (const float*)d_in[5];
  const int*   gas    = (const int*)d_in[6];
  float* out = (float*)d_out;

  const size_t nW = (size_t)V * H, nX = (size_t)BT * H;

  char* Wq = (char*)d_ws;                       // V*H fp8 (linear)
  char* Xt = Wq + nW;                           // BT*H fp8 (fragment-tiled)
  float* pM = (float*)(Xt + nX);
  float* pS = pM + (size_t)BT * NCHUNK;
  float* gold = pS + (size_t)BT * NCHUNK;
  float* rowterm = gold + BT;

  convert_fp8<<<dim3(2048), dim3(256), 0, stream>>>(Wt, Wq, (int)(nW / 8));
  convert_x_fp8_tiled<<<dim3(1024), dim3(256), 0, stream>>>(X, Xt,
                                                            (int)(nX / 8));
  gemm_lse_128<<<dim3(MT * NT), dim3(256), 0, stream>>>(Wq, Xt, target,
                                                        bias, pM, pS, gold);
  reduce_lse<<<dim3(BT / 4), dim3(256), 0, stream>>>(pM, pS, gold, target, lw,
                                                     rowterm);
  finalize<<<dim3(1), dim3(256), 0, stream>>>(rowterm, target, rsw, gas, out);
}

// Round 16
// 600.490 us; speedup vs baseline: 3.9144x; 3.9144x over previous
//
#include <hip/hip_runtime.h>
#include <hip/hip_bf16.h>
#include <math.h>

#define IGNORE_INDEX (-100)

constexpr int BT = 2048, H = 4096, V = 32000;
constexpr int BM = 256, BN = 256, BK = 64;
constexpr int KT = H / BK;            // 64 k-tiles
constexpr int MT2 = BT / BM;          // 8
constexpr int NT2 = V / BN;           // 125
constexpr int NCHUNK = NT2 * 4;       // 500 partial chunks/row (64 cols each)

typedef int   i32x4  __attribute__((ext_vector_type(4)));
typedef int   i32x8  __attribute__((ext_vector_type(8)));
typedef float f32x16 __attribute__((ext_vector_type(16)));

// e8m0 scale byte for 2^-7 (operands are pre-scaled by 2^7 at conversion)
#define SC8 120

__device__ __forceinline__ void gload_lds16(const char* g, char* l) {
  __builtin_amdgcn_global_load_lds(
      (const __attribute__((address_space(1))) unsigned int*)(g),
      (__attribute__((address_space(3))) unsigned int*)(l), 16, 0, 0);
}

#define BAR()        asm volatile("s_barrier" ::: "memory")
#define WAIT_VM(N)   asm volatile("s_waitcnt vmcnt(" #N ")" ::: "memory")
#define SB0()        __builtin_amdgcn_sched_barrier(0)

// ---------------------------------------------------------------------------
// fp32 -> fp8 e4m3 (OCP) bulk convert with x128 pre-scale  (r11-verified)
// ---------------------------------------------------------------------------
__global__ __launch_bounds__(256)
void convert_fp8(const float* __restrict__ src, char* __restrict__ dst,
                 int n8) {
  int i = blockIdx.x * blockDim.x + threadIdx.x;
  const int stride = gridDim.x * blockDim.x;
  for (; i < n8; i += stride) {
    const float4 f0 = ((const float4*)src)[2 * i];
    const float4 f1 = ((const float4*)src)[2 * i + 1];
    const float S = 128.f;
    int lo = 0, hi = 0;
    lo = __builtin_amdgcn_cvt_pk_fp8_f32(f0.x * S, f0.y * S, lo, false);
    lo = __builtin_amdgcn_cvt_pk_fp8_f32(f0.z * S, f0.w * S, lo, true);
    hi = __builtin_amdgcn_cvt_pk_fp8_f32(f1.x * S, f1.y * S, hi, false);
    hi = __builtin_amdgcn_cvt_pk_fp8_f32(f1.z * S, f1.w * S, hi, true);
    int2 v; v.x = lo; v.y = hi;
    ((int2*)dst)[i] = v;
  }
}

// ---------------------------------------------------------------------------
// 256x256 MX-fp8 GEMM (r11 data paths): [buf][256 rows][64 B] LDS regions,
// swizzle slot(row,q) = q ^ ((row>>1)&3) on BOTH sides (rule #21).
// r15 design, r16 FIX: main loop now uses RELATIVE tile offsets (asrc/bsrc
// advance 3*BK per iteration; r15 passed absolute T -> staged tile 2t+2,
// out-of-bounds reads -> fp8-NaN garbage).
// TRIPLE-buffered LDS (3 bufs/operand, 96KB) -> ONE barrier per K-tile with
// loads in flight across barriers (T4):
//  phase(rel D): STAGE(buf (D+2)%3, rel D+2); VM(4) [drains stages(D-1) ->
//            next phase's buf valid pre-BAR]; reads(buf D) interleaved with
//            MFMA4(mh0)/MFMA4(mh1); SB0; BAR.
// Audit (relative indexing): reads(T) use buf staged @T-2, drained at
// VM(4)@T-1 pre-BAR(T-1), reads after BAR(T-1) -> cross-wave safe.
// Overwrite: stage@T targets buf last read @T-1; those reads drain via lgkm
// waits before the SB0-pinned MFMAs pre-BAR(T-1); stage@T is post-BAR(T-1).
// Tail (tiles 60..63): VM(0)@tail-1 drains stages 62,63; audited.
// ---------------------------------------------------------------------------
__global__ __launch_bounds__(512, 2)
void gemm_lse_3buf(const char* __restrict__ Wq,   // (V,H) fp8, pre-scaled x128
                   const char* __restrict__ Xq,   // (BT,H) fp8, pre-scaled x128
                   const int* __restrict__ target,
                   const float* __restrict__ bias,
                   float* __restrict__ pM, float* __restrict__ pS,
                   float* __restrict__ gold)
{
  __shared__ char As[49152];   // [buf:3][256][64]
  __shared__ char Bs[49152];

  const int tid  = threadIdx.x;
  const int lane = tid & 63;
  const int wid  = tid >> 6;
  const int wr   = wid >> 2;        // 0..1 : rows [wr*128, +128)
  const int wcol = wid & 3;         // 0..3 : cols [wcol*64, +64)

  // XCD swizzle: nwg = 1000 = 8*125, bijective
  const int bid = (int)blockIdx.x;
  const int swz = (bid & 7) * 125 + (bid >> 3);
  const int mt = swz & (MT2 - 1);
  const int nt = swz >> 3;
  const int m0 = mt * BM, n0 = nt * BN;

  const int l31 = lane & 31;
  const int h   = lane >> 5;        // k-half owner
  // r11-verified swizzle: slot(row,q) = q ^ ((row>>1)&3)
  const int r2  = (l31 >> 1) & 3;
  const int s0  = ((2 * h) ^ r2) << 4;
  const int s1  = ((2 * h + 1) ^ r2) << 4;
  const int abase = (wr * 128 + l31) * 64;
  const int bbase = (wcol * 64 + l31) * 64;

  // staging: lane covers row lane>>2, slot lane&3; source pre-swizzled
  const int srow  = lane >> 2;
  const int sslot = ((lane & 3) ^ ((lane >> 3) & 3)) << 4;

  const char* asrc = Xq + (size_t)(m0 + wid * 32 + srow) * H + sslot;
  const char* bsrc = Wq + (size_t)(n0 + wid * 32 + srow) * H + sslot;

  f32x16 acc[4][2] = {};
  i32x8 aF0, aF1, bF0, bF1;

#define STAGE_A(BUF, DT)                                                      \
  { gload_lds16(asrc + (DT) * BK,                                             \
                &As[(BUF) * 16384 + wid * 2048 + lane * 16]);                 \
    gload_lds16(asrc + (size_t)16 * H + (DT) * BK,                            \
                &As[(BUF) * 16384 + wid * 2048 + 1024 + lane * 16]); }

#define STAGE_B(BUF, DT)                                                      \
  { gload_lds16(bsrc + (DT) * BK,                                             \
                &Bs[(BUF) * 16384 + wid * 2048 + lane * 16]);                 \
    gload_lds16(bsrc + (size_t)16 * H + (DT) * BK,                            \
                &Bs[(BUF) * 16384 + wid * 2048 + 1024 + lane * 16]); }

#define RDA(DST, BUF, MI)                                                     \
  { i32x4 lo = *(const i32x4*)&As[(BUF) * 16384 + abase + (MI) * 2048 + s0];  \
    i32x4 hi = *(const i32x4*)&As[(BUF) * 16384 + abase + (MI) * 2048 + s1];  \
    DST[0] = lo[0]; DST[1] = lo[1]; DST[2] = lo[2]; DST[3] = lo[3];           \
    DST[4] = hi[0]; DST[5] = hi[1]; DST[6] = hi[2]; DST[7] = hi[3]; }

#define RDB(DST, BUF, NJ)                                                     \
  { i32x4 lo = *(const i32x4*)&Bs[(BUF) * 16384 + bbase + (NJ) * 2048 + s0];  \
    i32x4 hi = *(const i32x4*)&Bs[(BUF) * 16384 + bbase + (NJ) * 2048 + s1];  \
    DST[0] = lo[0]; DST[1] = lo[1]; DST[2] = lo[2]; DST[3] = lo[3];           \
    DST[4] = hi[0]; DST[5] = hi[1]; DST[6] = hi[2]; DST[7] = hi[3]; }

#define MFMA4(MH)                                                             \
  { __builtin_amdgcn_s_setprio(1);                                            \
    acc[(MH)*2+0][0] = __builtin_amdgcn_mfma_scale_f32_32x32x64_f8f6f4(       \
        aF0, bF0, acc[(MH)*2+0][0], 0, 0, 0, SC8, 0, SC8);                    \
    acc[(MH)*2+0][1] = __builtin_amdgcn_mfma_scale_f32_32x32x64_f8f6f4(       \
        aF0, bF1, acc[(MH)*2+0][1], 0, 0, 0, SC8, 0, SC8);                    \
    acc[(MH)*2+1][0] = __builtin_amdgcn_mfma_scale_f32_32x32x64_f8f6f4(       \
        aF1, bF0, acc[(MH)*2+1][0], 0, 0, 0, SC8, 0, SC8);                    \
    acc[(MH)*2+1][1] = __builtin_amdgcn_mfma_scale_f32_32x32x64_f8f6f4(       \
        aF1, bF1, acc[(MH)*2+1][1], 0, 0, 0, SC8, 0, SC8);                    \
    __builtin_amdgcn_s_setprio(0); }

// full phase: tile at RELATIVE offset D (buf D), stage rel-tile D+2 into
// buf (D+2)%3 — all offsets relative to the current asrc/bsrc base.
#define PHASE(D, DOSTAGE, VMN)                                                \
  { if (DOSTAGE) { STAGE_B(((D) + 2) % 3, (D) + 2);                           \
                   STAGE_A(((D) + 2) % 3, (D) + 2); }                         \
    WAIT_VM(VMN);                                                             \
    RDA(aF0, (D) % 3, 0); RDA(aF1, (D) % 3, 1);                               \
    RDB(bF0, (D) % 3, 0); RDB(bF1, (D) % 3, 1);                               \
    MFMA4(0);                                                                 \
    RDA(aF0, (D) % 3, 2); RDA(aF1, (D) % 3, 3);                               \
    MFMA4(1);                                                                 \
    SB0(); BAR(); }

  // ---- prologue: stage tiles 0,1 (bufs 0,1); drain tile0; barrier
  STAGE_B(0, 0); STAGE_A(0, 0);
  STAGE_B(1, 1); STAGE_A(1, 1);
  WAIT_VM(4);                       // stages(0) landed; stages(1) in flight
  BAR();

  // ---- main loop: 3 K-tiles/iter, 1 barrier each; stages 2 tiles ahead.
  // RELATIVE offsets (r16 fix): tiles base+0,1,2; stages base+2,3,4.
  for (int it = 0; it < 20; ++it) {          // bases 0,3,...,57 -> tiles 0..59
    PHASE(0, 1, 4);
    PHASE(1, 1, 4);
    PHASE(2, 1, 4);
    asrc += 3 * BK; bsrc += 3 * BK;
  }
  // ---- tail: tiles 60..63 (asrc/bsrc at tile-60 base)
  PHASE(0, 1, 4);                   // tile 60 (buf0), stage 62 -> buf2
  PHASE(1, 1, 0);                   // tile 61 (buf1), stage 63 -> buf0,
                                    //   VM(0): drain all pre-BAR (tail-safe)
  PHASE(2, 0, 0);                   // tile 62 (buf2), no stage
  // tile 63 (buf0): reads only
  RDA(aF0, 0, 0); RDA(aF1, 0, 1); RDB(bF0, 0, 0); RDB(bF1, 0, 1);
  MFMA4(0);
  RDA(aF0, 0, 2); RDA(aF1, 0, 3);
  MFMA4(1);

#undef PHASE
#undef STAGE_A
#undef STAGE_B
#undef RDA
#undef RDB
#undef MFMA4

  // ---- epilogue (32x32 C/D: col=lane&31, row=(r&3)+8*(r>>2)+4*h) — verified
  const int colbase = n0 + wcol * 64;
  float bv[2];
#pragma unroll
  for (int nj = 0; nj < 2; ++nj) bv[nj] = bias[colbase + nj * 32 + l31];

  const int chunk = nt * 4 + wcol;
#pragma unroll
  for (int mi = 0; mi < 4; ++mi) {
#pragma unroll
    for (int r = 0; r < 16; ++r) {
      const int row = m0 + wr * 128 + mi * 32 + (r & 3) + 8 * (r >> 2) + 4 * h;
      const float v0 = acc[mi][0][r] + bv[0];
      const float v1 = acc[mi][1][r] + bv[1];
      float mx = fmaxf(v0, v1);
#pragma unroll
      for (int d = 1; d < 32; d <<= 1) mx = fmaxf(mx, __shfl_xor(mx, d));
      float s = expf(v0 - mx) + expf(v1 - mx);
#pragma unroll
      for (int d = 1; d < 32; d <<= 1) s += __shfl_xor(s, d);
      if (l31 == 0) {
        pM[(size_t)row * NCHUNK + chunk] = mx;
        pS[(size_t)row * NCHUNK + chunk] = s;
      }
      const int t = target[row];
      const int d0 = t - colbase;
      if (d0 >= 0 && d0 < 64 && l31 == (d0 & 31)) {
        gold[row] = (d0 >> 5) ? v1 : v0;
      }
    }
  }
}

// one wave per row: combine 500 (max, sumexp) chunks -> rowterm
__global__ __launch_bounds__(256)
void reduce_lse(const float* __restrict__ pM, const float* __restrict__ pS,
                const float* __restrict__ gold, const int* __restrict__ target,
                const float* __restrict__ lw, float* __restrict__ rowterm)
{
  const int wid = threadIdx.x >> 6, lane = threadIdx.x & 63;
  const int row = blockIdx.x * 4 + wid;
  if (row >= BT) return;
  const float* pm = pM + (size_t)row * NCHUNK;
  const float* ps = pS + (size_t)row * NCHUNK;
  float m = -INFINITY;
  for (int c2 = lane; c2 < NCHUNK; c2 += 64) m = fmaxf(m, pm[c2]);
#pragma unroll
  for (int d = 1; d < 64; d <<= 1) m = fmaxf(m, __shfl_xor(m, d));
  float s = 0.f;
  for (int c2 = lane; c2 < NCHUNK; c2 += 64) s += ps[c2] * expf(pm[c2] - m);
#pragma unroll
  for (int d = 1; d < 64; d <<= 1) s += __shfl_xor(s, d);
  if (lane == 0) {
    const int t = target[row];
    float term = 0.f;
    if (t != IGNORE_INDEX) term = (m + logf(s) - gold[row]) * lw[row];
    rowterm[row] = term;
  }
}

// single-block deterministic finalize
__global__ __launch_bounds__(256)
void finalize(const float* __restrict__ rowterm, const int* __restrict__ target,
              const float* __restrict__ rsw, const int* __restrict__ gas,
              float* __restrict__ out)
{
  __shared__ float sred[4];
  __shared__ int cred[4];
  const int tid = threadIdx.x;
  float s = 0.f;
  int cnt = 0;
  for (int i = tid; i < BT; i += 256) {
    s += rowterm[i];
    cnt += (target[i] != IGNORE_INDEX) ? 1 : 0;
  }
#pragma unroll
  for (int d = 1; d < 64; d <<= 1) {
    s += __shfl_xor(s, d);
    cnt += __shfl_xor(cnt, d);
  }
  const int wid = tid >> 6, lane = tid & 63;
  if (lane == 0) { sred[wid] = s; cred[wid] = cnt; }
  __syncthreads();
  if (tid == 0) {
    const float st = sred[0] + sred[1] + sred[2] + sred[3];
    const int ct = cred[0] + cred[1] + cred[2] + cred[3];
    const float n = (float)((ct > 0) ? ct : 1);
    const float rs = rsw[0];
    float loss = (rs == 0.f) ? 0.f : (st / n) / rs;
    loss /= (float)gas[0];
    out[0] = loss;
  }
}

extern "C" void kernel_launch(void* const* d_in, const int* in_sizes, int n_in,
                              void* d_out, int out_size, void* d_ws, size_t ws_size,
                              hipStream_t stream)
{
  const float* Wt     = (const float*)d_in[0];  // lin_weight (V,H)
  const float* X      = (const float*)d_in[1];  // _input (BT,H)
  const int*   target = (const int*)d_in[2];
  const float* bias   = (const float*)d_in[3];
  const float* lw     = (const float*)d_in[4];
  const float* rsw    = (const float*)d_in[5];
  const int*   gas    = (const int*)d_in[6];
  float* out = (float*)d_out;

  const size_t nW = (size_t)V * H, nX = (size_t)BT * H;

  char* Wq = (char*)d_ws;                       // V*H fp8
  char* Xq = Wq + nW;                           // BT*H fp8
  float* pM = (float*)(Xq + nX);
  float* pS = pM + (size_t)BT * NCHUNK;
  float* gold = pS + (size_t)BT * NCHUNK;
  float* rowterm = gold + BT;

  convert_fp8<<<dim3(2048), dim3(256), 0, stream>>>(Wt, Wq, (int)(nW / 8));
  convert_fp8<<<dim3(256), dim3(256), 0, stream>>>(X, Xq, (int)(nX / 8));
  gemm_lse_3buf<<<dim3(MT2 * NT2), dim3(512), 0, stream>>>(Wq, Xq, target,
                                                           bias, pM, pS, gold);
  reduce_lse<<<dim3(BT / 4), dim3(256), 0, stream>>>(pM, pS, gold, target, lw,
                                                     rowterm);
  finalize<<<dim3(1), dim3(256), 0, stream>>>(rowterm, target, rsw, gas, out);
}

// Round 17
// 590.195 us; speedup vs baseline: 3.9827x; 1.0174x over previous
//
#include <hip/hip_runtime.h>
#include <hip/hip_bf16.h>
#include <math.h>

#define IGNORE_INDEX (-100)

constexpr int BT = 2048, H = 4096, V = 32000;
constexpr int BM = 128, BN = 128, BK = 64;
constexpr int KT = H / BK;            // 64 k-tiles
constexpr int MT = BT / BM;           // 16
constexpr int NT = V / BN;            // 250
constexpr int NCHUNK = NT * 2;        // 500 partial chunks/row (64 cols each)

typedef int   i32x4  __attribute__((ext_vector_type(4)));
typedef int   i32x8  __attribute__((ext_vector_type(8)));
typedef float f32x16 __attribute__((ext_vector_type(16)));

// e8m0 scale byte for 2^-7 (operands are pre-scaled by 2^7 at conversion)
#define SC8 120

__device__ __forceinline__ void gload_lds16(const char* g, char* l) {
  __builtin_amdgcn_global_load_lds(
      (const __attribute__((address_space(1))) unsigned int*)(g),
      (__attribute__((address_space(3))) unsigned int*)(l), 16, 0, 0);
}

#define BAR()        asm volatile("s_barrier" ::: "memory")
#define WAIT_VM(N)   asm volatile("s_waitcnt vmcnt(" #N ")" ::: "memory")
#define SB0()        __builtin_amdgcn_sched_barrier(0)

// ---------------------------------------------------------------------------
// fp32 -> fp8 e4m3 (OCP) bulk convert with x128 pre-scale  (r11-verified)
// ---------------------------------------------------------------------------
__global__ __launch_bounds__(256)
void convert_fp8(const float* __restrict__ src, char* __restrict__ dst,
                 int n8) {
  int i = blockIdx.x * blockDim.x + threadIdx.x;
  const int stride = gridDim.x * blockDim.x;
  for (; i < n8; i += stride) {
    const float4 f0 = ((const float4*)src)[2 * i];
    const float4 f1 = ((const float4*)src)[2 * i + 1];
    const float S = 128.f;
    int lo = 0, hi = 0;
    lo = __builtin_amdgcn_cvt_pk_fp8_f32(f0.x * S, f0.y * S, lo, false);
    lo = __builtin_amdgcn_cvt_pk_fp8_f32(f0.z * S, f0.w * S, lo, true);
    hi = __builtin_amdgcn_cvt_pk_fp8_f32(f1.x * S, f1.y * S, hi, false);
    hi = __builtin_amdgcn_cvt_pk_fp8_f32(f1.z * S, f1.w * S, hi, true);
    int2 v; v.x = lo; v.y = hi;
    ((int2*)dst)[i] = v;
  }
}

// ---------------------------------------------------------------------------
// 128x128 MX-fp8 GEMM, 4-wave blocks, register-sized for 3 blocks/CU:
// acc[2][2] f32x16 = 64 regs; demand ~121 <= cap 170 (launch_bounds(256,3):
// 3 waves/EU -> per-wave unified cap 512/3). LDS 48KB/block -> 3 fit.
// Data paths: r11-verified LDS swizzle slot(row,q)=q^((row>>1)&3) BOTH sides;
// schedule: r16-VERIFIED 3-buffer 1-barrier relative-indexed phases (stage
// tile D+2 into buf (D+2)%3; VM(4)/phase drains stages(D-1) pre-BAR so
// reads(D) are cross-wave safe; overwrite gap = 2 barriers).
// ---------------------------------------------------------------------------
__global__ __launch_bounds__(256, 3)
void gemm_lse_o3(const char* __restrict__ Wq,   // (V,H) fp8, pre-scaled x128
                 const char* __restrict__ Xq,   // (BT,H) fp8, pre-scaled x128
                 const int* __restrict__ target,
                 const float* __restrict__ bias,
                 float* __restrict__ pM, float* __restrict__ pS,
                 float* __restrict__ gold)
{
  __shared__ char As[24576];   // [buf:3][128][64]
  __shared__ char Bs[24576];

  const int tid  = threadIdx.x;
  const int lane = tid & 63;
  const int wid  = tid >> 6;        // 0..3
  const int wr   = wid >> 1;        // 0..1 : rows [wr*64, +64)
  const int wc   = wid & 1;         // 0..1 : cols [wc*64, +64)

  // XCD swizzle: nwg = 4000 = 8*500, bijective
  const int bid = (int)blockIdx.x;
  const int swz = (bid & 7) * 500 + (bid >> 3);
  const int mt = swz & (MT - 1);
  const int nt = swz >> 4;          // 16 consecutive swz share one W panel
  const int m0 = mt * BM, n0 = nt * BN;

  const int l31 = lane & 31;
  const int h   = lane >> 5;        // k-half owner
  // r11-verified swizzle: slot(row,q) = q ^ ((row>>1)&3)
  const int r2  = (l31 >> 1) & 3;
  const int s0  = ((2 * h) ^ r2) << 4;
  const int s1  = ((2 * h + 1) ^ r2) << 4;
  const int abase = (wr * 64 + l31) * 64;
  const int bbase = (wc * 64 + l31) * 64;

  // staging: lane covers row lane>>2, slot lane&3; source pre-swizzled
  const int srow  = lane >> 2;
  const int sslot = ((lane & 3) ^ ((lane >> 3) & 3)) << 4;

  const char* asrc = Xq + (size_t)(m0 + wid * 32 + srow) * H + sslot;
  const char* bsrc = Wq + (size_t)(n0 + wid * 32 + srow) * H + sslot;

  f32x16 acc[2][2] = {};
  i32x8 aF0, aF1, bF0, bF1;

#define STAGE_A(BUF, DT)                                                      \
  { gload_lds16(asrc + (DT) * BK,                                             \
                &As[(BUF) * 8192 + wid * 2048 + lane * 16]);                  \
    gload_lds16(asrc + (size_t)16 * H + (DT) * BK,                            \
                &As[(BUF) * 8192 + wid * 2048 + 1024 + lane * 16]); }

#define STAGE_B(BUF, DT)                                                      \
  { gload_lds16(bsrc + (DT) * BK,                                             \
                &Bs[(BUF) * 8192 + wid * 2048 + lane * 16]);                  \
    gload_lds16(bsrc + (size_t)16 * H + (DT) * BK,                            \
                &Bs[(BUF) * 8192 + wid * 2048 + 1024 + lane * 16]); }

#define RDA(DST, BUF, MI)                                                     \
  { i32x4 lo = *(const i32x4*)&As[(BUF) * 8192 + abase + (MI) * 2048 + s0];   \
    i32x4 hi = *(const i32x4*)&As[(BUF) * 8192 + abase + (MI) * 2048 + s1];   \
    DST[0] = lo[0]; DST[1] = lo[1]; DST[2] = lo[2]; DST[3] = lo[3];           \
    DST[4] = hi[0]; DST[5] = hi[1]; DST[6] = hi[2]; DST[7] = hi[3]; }

#define RDB(DST, BUF, NJ)                                                     \
  { i32x4 lo = *(const i32x4*)&Bs[(BUF) * 8192 + bbase + (NJ) * 2048 + s0];   \
    i32x4 hi = *(const i32x4*)&Bs[(BUF) * 8192 + bbase + (NJ) * 2048 + s1];   \
    DST[0] = lo[0]; DST[1] = lo[1]; DST[2] = lo[2]; DST[3] = lo[3];           \
    DST[4] = hi[0]; DST[5] = hi[1]; DST[6] = hi[2]; DST[7] = hi[3]; }

#define MFMA4()                                                               \
  { __builtin_amdgcn_s_setprio(1);                                            \
    acc[0][0] = __builtin_amdgcn_mfma_scale_f32_32x32x64_f8f6f4(              \
        aF0, bF0, acc[0][0], 0, 0, 0, SC8, 0, SC8);                           \
    acc[0][1] = __builtin_amdgcn_mfma_scale_f32_32x32x64_f8f6f4(              \
        aF0, bF1, acc[0][1], 0, 0, 0, SC8, 0, SC8);                           \
    acc[1][0] = __builtin_amdgcn_mfma_scale_f32_32x32x64_f8f6f4(              \
        aF1, bF0, acc[1][0], 0, 0, 0, SC8, 0, SC8);                           \
    acc[1][1] = __builtin_amdgcn_mfma_scale_f32_32x32x64_f8f6f4(              \
        aF1, bF1, acc[1][1], 0, 0, 0, SC8, 0, SC8);                           \
    __builtin_amdgcn_s_setprio(0); }

// phase at RELATIVE tile offset D (buf D%3): stage rel-tile D+2 -> buf
// (D+2)%3; VM(4) drains stages(D-1) => buf D valid pre-BAR for all waves.
#define PHASE(D, DOSTAGE, VMN)                                                \
  { if (DOSTAGE) { STAGE_B(((D) + 2) % 3, (D) + 2);                           \
                   STAGE_A(((D) + 2) % 3, (D) + 2); }                         \
    WAIT_VM(VMN);                                                             \
    BAR();                                                                    \
    RDA(aF0, (D) % 3, 0); RDA(aF1, (D) % 3, 1);                               \
    RDB(bF0, (D) % 3, 0); RDB(bF1, (D) % 3, 1);                               \
    MFMA4();                                                                  \
    SB0(); }

  // ---- prologue: stage tiles 0,1 (bufs 0,1); drain tile0; (BAR in PHASE)
  STAGE_B(0, 0); STAGE_A(0, 0);
  STAGE_B(1, 1); STAGE_A(1, 1);
  // PHASE(0) below: no new stage? it stages tile 2 -> buf2; VM(4) keeps the
  // 4 just-issued (tile2), drains tiles 0,1 -> buf0 valid. BAR. reads buf0.

  // ---- main loop: 3 K-tiles/iter, 1 barrier each; stages 2 tiles ahead.
  for (int it = 0; it < 20; ++it) {          // bases 0,3,...,57 -> tiles 0..59
    PHASE(0, 1, 4);
    PHASE(1, 1, 4);
    PHASE(2, 1, 4);
    asrc += 3 * BK; bsrc += 3 * BK;
  }
  // ---- tail: tiles 60..63 (asrc/bsrc at tile-60 base)
  PHASE(0, 1, 4);                   // tile 60 (buf0), stage 62 -> buf2
  PHASE(1, 1, 0);                   // tile 61 (buf1), stage 63 -> buf0,
                                    //   VM(0): drain all pre-BAR (tail-safe)
  PHASE(2, 0, 0);                   // tile 62 (buf2), no stage
  // tile 63 (buf0): reads only (all DMAs drained at tail-1's VM(0))
  BAR();
  RDA(aF0, 0, 0); RDA(aF1, 0, 1); RDB(bF0, 0, 0); RDB(bF1, 0, 1);
  MFMA4();

#undef PHASE
#undef STAGE_A
#undef STAGE_B
#undef RDA
#undef RDB
#undef MFMA4

  // ---- epilogue (32x32 C/D: col=lane&31, row=(r&3)+8*(r>>2)+4*h) — verified
  const int colbase = n0 + wc * 64;
  float bv[2];
#pragma unroll
  for (int nj = 0; nj < 2; ++nj) bv[nj] = bias[colbase + nj * 32 + l31];

  const int chunk = nt * 2 + wc;
#pragma unroll
  for (int mi = 0; mi < 2; ++mi) {
#pragma unroll
    for (int r = 0; r < 16; ++r) {
      const int row = m0 + wr * 64 + mi * 32 + (r & 3) + 8 * (r >> 2) + 4 * h;
      const float v0 = acc[mi][0][r] + bv[0];
      const float v1 = acc[mi][1][r] + bv[1];
      float mx = fmaxf(v0, v1);
#pragma unroll
      for (int d = 1; d < 32; d <<= 1) mx = fmaxf(mx, __shfl_xor(mx, d));
      float s = expf(v0 - mx) + expf(v1 - mx);
#pragma unroll
      for (int d = 1; d < 32; d <<= 1) s += __shfl_xor(s, d);
      if (l31 == 0) {
        pM[(size_t)row * NCHUNK + chunk] = mx;
        pS[(size_t)row * NCHUNK + chunk] = s;
      }
      const int t = target[row];
      const int d0 = t - colbase;
      if (d0 >= 0 && d0 < 64 && l31 == (d0 & 31)) {
        gold[row] = (d0 >> 5) ? v1 : v0;
      }
    }
  }
}

// one wave per row: combine 500 (max, sumexp) chunks -> rowterm
__global__ __launch_bounds__(256)
void reduce_lse(const float* __restrict__ pM, const float* __restrict__ pS,
                const float* __restrict__ gold, const int* __restrict__ target,
                const float* __restrict__ lw, float* __restrict__ rowterm)
{
  const int wid = threadIdx.x >> 6, lane = threadIdx.x & 63;
  const int row = blockIdx.x * 4 + wid;
  if (row >= BT) return;
  const float* pm = pM + (size_t)row * NCHUNK;
  const float* ps = pS + (size_t)row * NCHUNK;
  float m = -INFINITY;
  for (int c2 = lane; c2 < NCHUNK; c2 += 64) m = fmaxf(m, pm[c2]);
#pragma unroll
  for (int d = 1; d < 64; d <<= 1) m = fmaxf(m, __shfl_xor(m, d));
  float s = 0.f;
  for (int c2 = lane; c2 < NCHUNK; c2 += 64) s += ps[c2] * expf(pm[c2] - m);
#pragma unroll
  for (int d = 1; d < 64; d <<= 1) s += __shfl_xor(s, d);
  if (lane == 0) {
    const int t = target[row];
    float term = 0.f;
    if (t != IGNORE_INDEX) term = (m + logf(s) - gold[row]) * lw[row];
    rowterm[row] = term;
  }
}

// single-block deterministic finalize
__global__ __launch_bounds__(256)
void finalize(const float* __restrict__ rowterm, const int* __restrict__ target,
              const float* __restrict__ rsw, const int* __restrict__ gas,
              float* __restrict__ out)
{
  __shared__ float sred[4];
  __shared__ int cred[4];
  const int tid = threadIdx.x;
  float s = 0.f;
  int cnt = 0;
  for (int i = tid; i < BT; i += 256) {
    s += rowterm[i];
    cnt += (target[i] != IGNORE_INDEX) ? 1 : 0;
  }
#pragma unroll
  for (int d = 1; d < 64; d <<= 1) {
    s += __shfl_xor(s, d);
    cnt += __shfl_xor(cnt, d);
  }
  const int wid = tid >> 6, lane = tid & 63;
  if (lane == 0) { sred[wid] = s; cred[wid] = cnt; }
  __syncthreads();
  if (tid == 0) {
    const float st = sred[0] + sred[1] + sred[2] + sred[3];
    const int ct = cred[0] + cred[1] + cred[2] + cred[3];
    const float n = (float)((ct > 0) ? ct : 1);
    const float rs = rsw[0];
    float loss = (rs == 0.f) ? 0.f : (st / n) / rs;
    loss /= (float)gas[0];
    out[0] = loss;
  }
}

extern "C" void kernel_launch(void* const* d_in, const int* in_sizes, int n_in,
                              void* d_out, int out_size, void* d_ws, size_t ws_size,
                              hipStream_t stream)
{
  const float* Wt     = (const float*)d_in[0];  // lin_weight (V,H)
  const float* X      = (const float*)d_in[1];  // _input (BT,H)
  const int*   target = (const int*)d_in[2];
  const float* bias   = (const float*)d_in[3];
  const float* lw     = (const float*)d_in[4];
  const float* rsw    = (const float*)d_in[5];
  const int*   gas    = (const int*)d_in[6];
  float* out = (float*)d_out;

  const size_t nW = (size_t)V * H, nX = (size_t)BT * H;

  char* Wq = (char*)d_ws;                       // V*H fp8
  char* Xq = Wq + nW;                           // BT*H fp8
  float* pM = (float*)(Xq + nX);
  float* pS = pM + (size_t)BT * NCHUNK;
  float* gold = pS + (size_t)BT * NCHUNK;
  float* rowterm = gold + BT;

  convert_fp8<<<dim3(2048), dim3(256), 0, stream>>>(Wt, Wq, (int)(nW / 8));
  convert_fp8<<<dim3(256), dim3(256), 0, stream>>>(X, Xq, (int)(nX / 8));
  gemm_lse_o3<<<dim3(MT * NT), dim3(256), 0, stream>>>(Wq, Xq, target,
                                                       bias, pM, pS, gold);
  reduce_lse<<<dim3(BT / 4), dim3(256), 0, stream>>>(pM, pS, gold, target, lw,
                                                     rowterm);
  finalize<<<dim3(1), dim3(256), 0, stream>>>(rowterm, target, rsw, gas, out);
}

// Round 18
// 549.179 us; speedup vs baseline: 4.2802x; 1.0747x over previous
//
#include <hip/hip_runtime.h>
#include <hip/hip_bf16.h>
#include <math.h>

#define IGNORE_INDEX (-100)

constexpr int BT = 2048, H = 4096, V = 32000;
constexpr int BM = 256, BN = 256, BK = 64;
constexpr int KT = H / BK;            // 64 k-tiles
constexpr int MT2 = BT / BM;          // 8
constexpr int NT2 = V / BN;           // 125
constexpr int NCHUNK = NT2 * 4;       // 500 partial chunks/row (64 cols each)

typedef int   i32x4  __attribute__((ext_vector_type(4)));
typedef int   i32x8  __attribute__((ext_vector_type(8)));
typedef float f32x16 __attribute__((ext_vector_type(16)));

// e8m0 scale byte for 2^-7 (operands are pre-scaled by 2^7 at conversion)
#define SC8 120

__device__ __forceinline__ void gload_lds16(const char* g, char* l) {
  __builtin_amdgcn_global_load_lds(
      (const __attribute__((address_space(1))) unsigned int*)(g),
      (__attribute__((address_space(3))) unsigned int*)(l), 16, 0, 0);
}

#define BAR()        asm volatile("s_barrier" ::: "memory")
#define WAIT_VM(N)   asm volatile("s_waitcnt vmcnt(" #N ")" ::: "memory")

// ---------------------------------------------------------------------------
// fp32 -> fp8 e4m3 (OCP) bulk convert with x128 pre-scale
// ---------------------------------------------------------------------------
__global__ __launch_bounds__(256)
void convert_fp8(const float* __restrict__ src, char* __restrict__ dst,
                 int n8) {
  int i = blockIdx.x * blockDim.x + threadIdx.x;
  const int stride = gridDim.x * blockDim.x;
  for (; i < n8; i += stride) {
    const float4 f0 = ((const float4*)src)[2 * i];
    const float4 f1 = ((const float4*)src)[2 * i + 1];
    const float S = 128.f;
    int lo = 0, hi = 0;
    lo = __builtin_amdgcn_cvt_pk_fp8_f32(f0.x * S, f0.y * S, lo, false);
    lo = __builtin_amdgcn_cvt_pk_fp8_f32(f0.z * S, f0.w * S, lo, true);
    hi = __builtin_amdgcn_cvt_pk_fp8_f32(f1.x * S, f1.y * S, hi, false);
    hi = __builtin_amdgcn_cvt_pk_fp8_f32(f1.z * S, f1.w * S, hi, true);
    int2 v; v.x = lo; v.y = hi;
    ((int2*)dst)[i] = v;
  }
}

// ---------------------------------------------------------------------------
// 256x256 MX-fp8 GEMM: mfma_scale_f32_32x32x64_f8f6f4, uniform e8m0 scales.
// LDS: per operand [buf:2][256 rows][64 B] = 32KB -> 64KB total.
// SWIZZLE (r11-verified): stored 16B-slot(row, q) = q ^ ((row>>1)&3).
//   Bank-window position(row,slot) = (row&1)*4 + slot; with (row>>1)&3 in the
//   XOR, position is bijective over row mod 8 -> every hardware oct-group
//   (8 lanes x 16B = 128B) covers all 32 banks.
// Staged linear-dest via pre-swizzled source quad (lane&3)^((lane>>3)&3)
// (rule #21: write-side permutation == read-side permutation).
// Schedule: 4 phases / 2 K-tiles, 1 stage-region + VM(2) + BAR per phase,
// reads post-BAR (compiler counted lgkm waits before MFMA).
//  Region audit (stage p vs last read q: reads(q) drain < MFMA(q) < BAR(q+1)
//  <= BAR(p-1) < stage(p), need p >= q+2):
//   B(b0) read P1 -> staged P3 ✓   A(b0) read P1,P2 -> staged P4 ✓
//   B(b1) read P3 -> staged P1' ✓  A(b1) read P3,P4 -> staged P2' ✓
//  DMA-drain: VM(2)@p (pre-BAR) drains the stages of p-2,p-1 in every wave;
//  BAR(p) then orders them before reads(p) -> cross-wave safe.
//  B-frags carried in regs across the tile's two phases (read once).
// ---------------------------------------------------------------------------
__global__ __launch_bounds__(512, 2)
void gemm_lse_fp8(const char* __restrict__ Wq,   // (V,H) fp8, pre-scaled x128
                  const char* __restrict__ Xq,   // (BT,H) fp8, pre-scaled x128
                  const int* __restrict__ target,
                  const float* __restrict__ bias,
                  float* __restrict__ pM, float* __restrict__ pS,
                  float* __restrict__ gold)
{
  __shared__ char As[32768];   // [buf:2][256][64]
  __shared__ char Bs[32768];

  const int tid  = threadIdx.x;
  const int lane = tid & 63;
  const int wid  = tid >> 6;
  const int wr   = wid >> 2;        // 0..1 : rows [wr*128, +128)
  const int wcol = wid & 3;         // 0..3 : cols [wcol*64, +64)

  // XCD swizzle: nwg = 1000 = 8*125, bijective
  const int bid = (int)blockIdx.x;
  const int swz = (bid & 7) * 125 + (bid >> 3);
  const int mt = swz & (MT2 - 1);
  const int nt = swz >> 3;
  const int m0 = mt * BM, n0 = nt * BN;

  const int l31 = lane & 31;
  const int h   = lane >> 5;        // k-half owner: k in [h*32, h*32+32)
  const int r2  = (l31 >> 1) & 3;   // (row>>1)&3 (invariant under +8 rows)
  const int s0  = ((2 * h) ^ r2) << 4;       // stored slot of k-bytes 0..15
  const int s1  = ((2 * h + 1) ^ r2) << 4;   // stored slot of k-bytes 16..31
  const int abase = (wr * 128 + l31) * 64;
  const int bbase = (wcol * 64 + l31) * 64;

  // staging: lane covers row (lane>>2), slot lane&3; source pre-swizzled:
  // q = slot ^ ((row>>1)&3) = (lane&3) ^ ((lane>>3)&3)
  const int srow  = lane >> 2;
  const int sslot = ((lane & 3) ^ ((lane >> 3) & 3)) << 4;

  const char* asrc = Xq + (size_t)(m0 + wid * 32 + srow) * H + sslot;
  const char* bsrc = Wq + (size_t)(n0 + wid * 32 + srow) * H + sslot;

  f32x16 acc[4][2] = {};
  i32x8 aF0, aF1, bF0, bF1;

#define STAGE_A(BUF, DT)                                                      \
  { gload_lds16(asrc + (DT) * BK,                                             \
                &As[(BUF) * 16384 + wid * 2048 + lane * 16]);                 \
    gload_lds16(asrc + (size_t)16 * H + (DT) * BK,                            \
                &As[(BUF) * 16384 + wid * 2048 + 1024 + lane * 16]); }

#define STAGE_B(BUF, DT)                                                      \
  { gload_lds16(bsrc + (DT) * BK,                                             \
                &Bs[(BUF) * 16384 + wid * 2048 + lane * 16]);                 \
    gload_lds16(bsrc + (size_t)16 * H + (DT) * BK,                            \
                &Bs[(BUF) * 16384 + wid * 2048 + 1024 + lane * 16]); }

#define RDA(DST, BUF, MI)                                                     \
  { i32x4 lo = *(const i32x4*)&As[(BUF) * 16384 + abase + (MI) * 2048 + s0];  \
    i32x4 hi = *(const i32x4*)&As[(BUF) * 16384 + abase + (MI) * 2048 + s1];  \
    DST[0] = lo[0]; DST[1] = lo[1]; DST[2] = lo[2]; DST[3] = lo[3];           \
    DST[4] = hi[0]; DST[5] = hi[1]; DST[6] = hi[2]; DST[7] = hi[3]; }

#define RDB(DST, BUF, NJ)                                                     \
  { i32x4 lo = *(const i32x4*)&Bs[(BUF) * 16384 + bbase + (NJ) * 2048 + s0];  \
    i32x4 hi = *(const i32x4*)&Bs[(BUF) * 16384 + bbase + (NJ) * 2048 + s1];  \
    DST[0] = lo[0]; DST[1] = lo[1]; DST[2] = lo[2]; DST[3] = lo[3];           \
    DST[4] = hi[0]; DST[5] = hi[1]; DST[6] = hi[2]; DST[7] = hi[3]; }

#define MFMA4(MH)                                                             \
  { __builtin_amdgcn_s_setprio(1);                                            \
    acc[(MH)*2+0][0] = __builtin_amdgcn_mfma_scale_f32_32x32x64_f8f6f4(       \
        aF0, bF0, acc[(MH)*2+0][0], 0, 0, 0, SC8, 0, SC8);                    \
    acc[(MH)*2+0][1] = __builtin_amdgcn_mfma_scale_f32_32x32x64_f8f6f4(       \
        aF0, bF1, acc[(MH)*2+0][1], 0, 0, 0, SC8, 0, SC8);                    \
    acc[(MH)*2+1][0] = __builtin_amdgcn_mfma_scale_f32_32x32x64_f8f6f4(       \
        aF1, bF0, acc[(MH)*2+1][0], 0, 0, 0, SC8, 0, SC8);                    \
    acc[(MH)*2+1][1] = __builtin_amdgcn_mfma_scale_f32_32x32x64_f8f6f4(       \
        aF1, bF1, acc[(MH)*2+1][1], 0, 0, 0, SC8, 0, SC8);                    \
    __builtin_amdgcn_s_setprio(0); }

  // ---- prologue: tile0 -> buf0 (4 loads in flight)
  STAGE_B(0, 0); STAGE_A(0, 0);

  // ---- main loop: 2 K-tiles/iter, 4 phases, 1 barrier each
  for (int t = 0; t <= KT - 4; t += 2) {
    // P1: stage B(b1)<-t+1; VM(2) drains b0's stages; compute (b0, mh0)
    STAGE_B(1, 1);
    WAIT_VM(2); BAR();
    RDA(aF0, 0, 0); RDA(aF1, 0, 1); RDB(bF0, 0, 0); RDB(bF1, 0, 1);
    MFMA4(0);
    // P2: stage A(b1)<-t+1; compute (b0, mh1)  [B carried in regs]
    STAGE_A(1, 1);
    WAIT_VM(2); BAR();
    RDA(aF0, 0, 2); RDA(aF1, 0, 3);
    MFMA4(1);
    // P3: stage B(b0)<-t+2; VM(2) drains b1's stages; compute (b1, mh0)
    STAGE_B(0, 2);
    WAIT_VM(2); BAR();
    RDA(aF0, 1, 0); RDA(aF1, 1, 1); RDB(bF0, 1, 0); RDB(bF1, 1, 1);
    MFMA4(0);
    // P4: stage A(b0)<-t+2; compute (b1, mh1)
    STAGE_A(0, 2);
    WAIT_VM(2); BAR();
    RDA(aF0, 1, 2); RDA(aF1, 1, 3);
    MFMA4(1);

    asrc += 2 * BK; bsrc += 2 * BK;
  }

  // ---- tail: tiles KT-2 (b0), KT-1 (b1)
  STAGE_B(1, 1);
  WAIT_VM(2); BAR();
  RDA(aF0, 0, 0); RDA(aF1, 0, 1); RDB(bF0, 0, 0); RDB(bF1, 0, 1);
  MFMA4(0);
  STAGE_A(1, 1);
  WAIT_VM(2); BAR();
  RDA(aF0, 0, 2); RDA(aF1, 0, 3);
  MFMA4(1);
  WAIT_VM(0); BAR();
  RDA(aF0, 1, 0); RDA(aF1, 1, 1); RDB(bF0, 1, 0); RDB(bF1, 1, 1);
  MFMA4(0);
  RDA(aF0, 1, 2); RDA(aF1, 1, 3);
  MFMA4(1);

#undef STAGE_A
#undef STAGE_B
#undef RDA
#undef RDB
#undef MFMA4

  // ---- epilogue (32x32 C/D: col=lane&31, row=(r&3)+8*(r>>2)+4*h) — verified
  const int colbase = n0 + wcol * 64;
  float bv[2];
#pragma unroll
  for (int nj = 0; nj < 2; ++nj) bv[nj] = bias[colbase + nj * 32 + l31];

  const int chunk = nt * 4 + wcol;
#pragma unroll
  for (int mi = 0; mi < 4; ++mi) {
#pragma unroll
    for (int r = 0; r < 16; ++r) {
      const int row = m0 + wr * 128 + mi * 32 + (r & 3) + 8 * (r >> 2) + 4 * h;
      const float v0 = acc[mi][0][r] + bv[0];
      const float v1 = acc[mi][1][r] + bv[1];
      float mx = fmaxf(v0, v1);
#pragma unroll
      for (int d = 1; d < 32; d <<= 1) mx = fmaxf(mx, __shfl_xor(mx, d));
      float s = expf(v0 - mx) + expf(v1 - mx);
#pragma unroll
      for (int d = 1; d < 32; d <<= 1) s += __shfl_xor(s, d);
      if (l31 == 0) {
        pM[(size_t)row * NCHUNK + chunk] = mx;
        pS[(size_t)row * NCHUNK + chunk] = s;
      }
      const int t = target[row];
      const int d0 = t - colbase;
      if (d0 >= 0 && d0 < 64 && l31 == (d0 & 31)) {
        gold[row] = (d0 >> 5) ? v1 : v0;
      }
    }
  }
}

// one wave per row: combine 500 (max, sumexp) chunks -> rowterm
__global__ __launch_bounds__(256)
void reduce_lse(const float* __restrict__ pM, const float* __restrict__ pS,
                const float* __restrict__ gold, const int* __restrict__ target,
                const float* __restrict__ lw, float* __restrict__ rowterm)
{
  const int wid = threadIdx.x >> 6, lane = threadIdx.x & 63;
  const int row = blockIdx.x * 4 + wid;
  if (row >= BT) return;
  const float* pm = pM + (size_t)row * NCHUNK;
  const float* ps = pS + (size_t)row * NCHUNK;
  float m = -INFINITY;
  for (int c2 = lane; c2 < NCHUNK; c2 += 64) m = fmaxf(m, pm[c2]);
#pragma unroll
  for (int d = 1; d < 64; d <<= 1) m = fmaxf(m, __shfl_xor(m, d));
  float s = 0.f;
  for (int c2 = lane; c2 < NCHUNK; c2 += 64) s += ps[c2] * expf(pm[c2] - m);
#pragma unroll
  for (int d = 1; d < 64; d <<= 1) s += __shfl_xor(s, d);
  if (lane == 0) {
    const int t = target[row];
    float term = 0.f;
    if (t != IGNORE_INDEX) term = (m + logf(s) - gold[row]) * lw[row];
    rowterm[row] = term;
  }
}

// single-block deterministic finalize
__global__ __launch_bounds__(256)
void finalize(const float* __restrict__ rowterm, const int* __restrict__ target,
              const float* __restrict__ rsw, const int* __restrict__ gas,
              float* __restrict__ out)
{
  __shared__ float sred[4];
  __shared__ int cred[4];
  const int tid = threadIdx.x;
  float s = 0.f;
  int cnt = 0;
  for (int i = tid; i < BT; i += 256) {
    s += rowterm[i];
    cnt += (target[i] != IGNORE_INDEX) ? 1 : 0;
  }
#pragma unroll
  for (int d = 1; d < 64; d <<= 1) {
    s += __shfl_xor(s, d);
    cnt += __shfl_xor(cnt, d);
  }
  const int wid = tid >> 6, lane = tid & 63;
  if (lane == 0) { sred[wid] = s; cred[wid] = cnt; }
  __syncthreads();
  if (tid == 0) {
    const float st = sred[0] + sred[1] + sred[2] + sred[3];
    const int ct = cred[0] + cred[1] + cred[2] + cred[3];
    const float n = (float)((ct > 0) ? ct : 1);
    const float rs = rsw[0];
    float loss = (rs == 0.f) ? 0.f : (st / n) / rs;
    loss /= (float)gas[0];
    out[0] = loss;
  }
}

extern "C" void kernel_launch(void* const* d_in, const int* in_sizes, int n_in,
                              void* d_out, int out_size, void* d_ws, size_t ws_size,
                              hipStream_t stream)
{
  const float* Wt     = (const float*)d_in[0];  // lin_weight (V,H)
  const float* X      = (const float*)d_in[1];  // _input (BT,H)
  const int*   target = (const int*)d_in[2];
  const float* bias   = (const float*)d_in[3];
  const float* lw     = (const float*)d_in[4];
  const float* rsw    = (const float*)d_in[5];
  const int*   gas    = (const int*)d_in[6];
  float* out = (float*)d_out;

  const size_t nW = (size_t)V * H, nX = (size_t)BT * H;

  char* Wq = (char*)d_ws;                       // V*H fp8
  char* Xq = Wq + nW;                           // BT*H fp8
  float* pM = (float*)(Xq + nX);
  float* pS = pM + (size_t)BT * NCHUNK;
  float* gold = pS + (size_t)BT * NCHUNK;
  float* rowterm = gold + BT;

  convert_fp8<<<dim3(2048), dim3(256), 0, stream>>>(Wt, Wq, (int)(nW / 8));
  convert_fp8<<<dim3(256), dim3(256), 0, stream>>>(X, Xq, (int)(nX / 8));
  gemm_lse_fp8<<<dim3(MT2 * NT2), dim3(512), 0, stream>>>(Wq, Xq, target,
                                                          bias, pM, pS, gold);
  reduce_lse<<<dim3(BT / 4), dim3(256), 0, stream>>>(pM, pS, gold, target, lw,
                                                     rowterm);
  finalize<<<dim3(1), dim3(256), 0, stream>>>(rowterm, target, rsw, gas, out);
}